// Round 1
// baseline (320.669 us; speedup 1.0000x reference)
//
#include <hip/hip_runtime.h>

typedef __attribute__((ext_vector_type(8))) short bhalf8;   // 8 bf16 MFMA operand
typedef __attribute__((ext_vector_type(4))) float f32x4;
typedef __attribute__((ext_vector_type(8))) unsigned short u16x8;
typedef __attribute__((ext_vector_type(4))) unsigned short u16x4;

#define BDIM 2
#define SDIM 2048
#define DDIM 1024
#define HDIM 16
#define HDHD 64

__device__ __forceinline__ unsigned short f2bf(float f) {
  unsigned u = __builtin_bit_cast(unsigned, f);
  u += 0x7fffu + ((u >> 16) & 1u);           // RNE
  return (unsigned short)(u >> 16);
}

// ---------------- elementwise f32 -> bf16 ----------------
__global__ __launch_bounds__(256) void cvt_hidden(const float* __restrict__ x,
                                                  unsigned short* __restrict__ y) {
  size_t i = ((size_t)blockIdx.x * 256 + threadIdx.x) * 4;
  f32x4 v = *(const f32x4*)(x + i);
  u16x4 o;
  o[0] = f2bf(v[0]); o[1] = f2bf(v[1]); o[2] = f2bf(v[2]); o[3] = f2bf(v[3]);
  *(u16x4*)(y + i) = o;
}

// ---------------- transpose + convert: W[R][C] f32 -> Wt[C][R] bf16 ----------------
__global__ __launch_bounds__(256) void transpose_cvt(const float* __restrict__ W,
                                                     unsigned short* __restrict__ Wt,
                                                     int R, int C) {
  __shared__ float tl[32][33];
  int rt = blockIdx.x * 32, ct = blockIdx.y * 32;
  int r8 = threadIdx.x >> 5, c = threadIdx.x & 31;
#pragma unroll
  for (int i = 0; i < 4; i++)
    tl[r8 + i * 8][c] = W[(size_t)(rt + r8 + i * 8) * C + ct + c];
  __syncthreads();
#pragma unroll
  for (int i = 0; i < 4; i++)
    Wt[(size_t)(ct + r8 + i * 8) * R + rt + c] = f2bf(tl[c][r8 + i * 8]);
}

// ------- W'^T[o][h*64+d] = sum_e P[h][d][e] * Wproj[h*64+e][o]  (bf16 out) -------
__global__ __launch_bounds__(256) void make_wproj(const float* __restrict__ proj,
                                                  const float* __restrict__ wproj,
                                                  unsigned short* __restrict__ WT) {
  int h = blockIdx.x, ot = blockIdx.y * 64;
  __shared__ float Pl[64][65];
  __shared__ float Wl[64][65];
  int t = threadIdx.x;
#pragma unroll
  for (int i = 0; i < 16; i++) {
    int idx = t + 256 * i;                  // 0..4095
    int a = idx >> 6, bc = idx & 63;
    Pl[a][bc] = proj[(size_t)h * 4096 + idx];
    Wl[a][bc] = wproj[(size_t)(h * 64 + a) * 1024 + ot + bc];
  }
  __syncthreads();
  int d = t & 63, ob = t >> 6;              // lanes vary d -> coalesced writes
#pragma unroll
  for (int i = 0; i < 16; i++) {
    int o = ob + i * 4;
    float acc = 0.f;
#pragma unroll
    for (int e = 0; e < 64; e++) acc += Pl[d][e] * Wl[e][o];
    WT[(size_t)(ot + o) * 1024 + h * 64 + d] = f2bf(acc);
  }
}

// ---------------- bf16 GEMM, Bt layout: C[M,N] = A[M,K] @ Bt[N,K]^T + bias ----------------
// EPI 0: split into q(,*0.125)/k/v  [B,H,S,HD] bf16.  EPI 1: f32 out row-major.
template <int EPI>
__global__ __launch_bounds__(256) void gemm_bt(
    const unsigned short* __restrict__ A, const unsigned short* __restrict__ Bt,
    const float* __restrict__ bias, float* __restrict__ Cf,
    unsigned short* __restrict__ q, unsigned short* __restrict__ k,
    unsigned short* __restrict__ v, int M, int N, int K) {
  __shared__ unsigned short As[128][72];
  __shared__ unsigned short Bs[128][72];
  const int tid = threadIdx.x;
  const int m0 = blockIdx.y * 128, n0 = blockIdx.x * 128;
  f32x4 acc[4][4];
#pragma unroll
  for (int m = 0; m < 4; m++)
#pragma unroll
    for (int n = 0; n < 4; n++) acc[m][n] = f32x4{0.f, 0.f, 0.f, 0.f};
  const int w = tid >> 6, lane = tid & 63;
  const int wr = (w >> 1) * 64, wc = (w & 1) * 64;
  const int lrow = lane & 15, lk = (lane >> 4) * 8;

  for (int kt = 0; kt < K; kt += 64) {
    __syncthreads();
#pragma unroll
    for (int i = 0; i < 4; i++) {
      int cch = tid + 256 * i;              // 0..1023 chunks of 8 bf16
      int r = cch >> 3, c8 = cch & 7;
      *(u16x8*)(&As[r][c8 * 8]) = *(const u16x8*)(A + (size_t)(m0 + r) * K + kt + c8 * 8);
      *(u16x8*)(&Bs[r][c8 * 8]) = *(const u16x8*)(Bt + (size_t)(n0 + r) * K + kt + c8 * 8);
    }
    __syncthreads();
#pragma unroll
    for (int kk = 0; kk < 2; kk++) {
      bhalf8 af[4], bfr[4];
#pragma unroll
      for (int m = 0; m < 4; m++) af[m] = *(const bhalf8*)(&As[wr + m * 16 + lrow][kk * 32 + lk]);
#pragma unroll
      for (int n = 0; n < 4; n++) bfr[n] = *(const bhalf8*)(&Bs[wc + n * 16 + lrow][kk * 32 + lk]);
#pragma unroll
      for (int m = 0; m < 4; m++)
#pragma unroll
        for (int n = 0; n < 4; n++)
          acc[m][n] = __builtin_amdgcn_mfma_f32_16x16x32_bf16(af[m], bfr[n], acc[m][n], 0, 0, 0);
    }
  }
  // epilogue: D row = 4*(lane>>4)+r, col = lane&15 within each 16x16 frag
  const int g = lane >> 4, il = lane & 15;
#pragma unroll
  for (int m = 0; m < 4; m++) {
    int rowb = wr + m * 16 + 4 * g;
#pragma unroll
    for (int n = 0; n < 4; n++) {
      int col = n0 + wc + n * 16 + il;
      float bs = bias[col];
#pragma unroll
      for (int r = 0; r < 4; r++) {
        int row = m0 + rowb + r;
        float val = acc[m][n][r] + bs;
        if (EPI == 0) {
          int which = col >> 10, hh = (col >> 6) & 15, hd = col & 63;
          int b = row >> 11, s = row & 2047;
          size_t idx = ((size_t)(b * 16 + hh) * SDIM + s) * HDHD + hd;
          unsigned short bv = f2bf(which == 0 ? val * 0.125f : val);
          if (which == 0) q[idx] = bv;
          else if (which == 1) k[idx] = bv;
          else v[idx] = bv;
        } else {
          Cf[(size_t)row * N + col] = val;
        }
      }
    }
  }
}

// ---------------- causal flash attention, writes merged [B*S][D] bf16 ----------------
__global__ __launch_bounds__(256) void attn_kernel(const unsigned short* __restrict__ Q,
                                                   const unsigned short* __restrict__ Kb,
                                                   const unsigned short* __restrict__ Vb,
                                                   unsigned short* __restrict__ Om) {
  __shared__ unsigned short Ks[32][72];
  __shared__ unsigned short Vts[64][40];
  __shared__ unsigned short Ps[4][16][40];
  const int qt = blockIdx.x;              // q tile of 64 rows
  const int bh = blockIdx.y;              // b*16+h
  const int tid = threadIdx.x;
  const int w = tid >> 6, lane = tid & 63;
  const int g = lane >> 4, il = lane & 15;
  const int lk = g * 8;
  const int qbase = qt * 64 + w * 16;
  const size_t bhS = (size_t)bh * SDIM;

  bhalf8 qf0, qf1;
  {
    const unsigned short* qp = Q + (bhS + qbase + il) * HDHD;
    qf0 = *(const bhalf8*)(qp + lk);
    qf1 = *(const bhalf8*)(qp + 32 + lk);
  }
  f32x4 oacc[4];
#pragma unroll
  for (int i = 0; i < 4; i++) oacc[i] = f32x4{0.f, 0.f, 0.f, 0.f};
  float mrun[4], lrun[4];
#pragma unroll
  for (int r = 0; r < 4; r++) { mrun[r] = -1e30f; lrun[r] = 0.f; }

  const int ktiles = 2 * qt + 2;
  for (int kt = 0; kt < ktiles; kt++) {
    __syncthreads();
    {
      int r = tid >> 3, c8 = (tid & 7) * 8;
      *(u16x8*)(&Ks[r][c8]) = *(const u16x8*)(Kb + (bhS + kt * 32 + r) * HDHD + c8);
      u16x8 vv = *(const u16x8*)(Vb + (bhS + kt * 32 + r) * HDHD + c8);
#pragma unroll
      for (int j = 0; j < 8; j++) Vts[c8 + j][r] = vv[j];   // V transposed in LDS
    }
    __syncthreads();
    // S tile = Q @ K^T   (16 q-rows x 32 k-cols per wave)
    f32x4 s0 = f32x4{0.f, 0.f, 0.f, 0.f}, s1 = f32x4{0.f, 0.f, 0.f, 0.f};
    {
      bhalf8 k00 = *(const bhalf8*)(&Ks[il][lk]);
      bhalf8 k01 = *(const bhalf8*)(&Ks[il][32 + lk]);
      bhalf8 k10 = *(const bhalf8*)(&Ks[16 + il][lk]);
      bhalf8 k11 = *(const bhalf8*)(&Ks[16 + il][32 + lk]);
      s0 = __builtin_amdgcn_mfma_f32_16x16x32_bf16(qf0, k00, s0, 0, 0, 0);
      s0 = __builtin_amdgcn_mfma_f32_16x16x32_bf16(qf1, k01, s0, 0, 0, 0);
      s1 = __builtin_amdgcn_mfma_f32_16x16x32_bf16(qf0, k10, s1, 0, 0, 0);
      s1 = __builtin_amdgcn_mfma_f32_16x16x32_bf16(qf1, k11, s1, 0, 0, 0);
    }
    const int kc = kt * 32 + il;
#pragma unroll
    for (int r = 0; r < 4; r++) {
      float sv0 = s0[r], sv1 = s1[r];
      int qr = qbase + 4 * g + r;
      if (kc > qr) sv0 = -1e30f;
      if (kc + 16 > qr) sv1 = -1e30f;
      float mx = fmaxf(sv0, sv1);
#pragma unroll
      for (int d = 1; d < 16; d <<= 1) mx = fmaxf(mx, __shfl_xor(mx, d));
      float mn = fmaxf(mrun[r], mx);
      float sc = __expf(mrun[r] - mn);
      mrun[r] = mn;
      float p0 = __expf(sv0 - mn);
      float p1 = __expf(sv1 - mn);
      float rs = p0 + p1;
#pragma unroll
      for (int d = 1; d < 16; d <<= 1) rs += __shfl_xor(rs, d);
      lrun[r] = lrun[r] * sc + rs;
      Ps[w][4 * g + r][il] = f2bf(p0);
      Ps[w][4 * g + r][16 + il] = f2bf(p1);
#pragma unroll
      for (int hf = 0; hf < 4; hf++) oacc[hf][r] *= sc;
    }
    // O += P @ V
    bhalf8 pf = *(const bhalf8*)(&Ps[w][il][lk]);
#pragma unroll
    for (int hf = 0; hf < 4; hf++) {
      bhalf8 vf = *(const bhalf8*)(&Vts[hf * 16 + il][lk]);
      oacc[hf] = __builtin_amdgcn_mfma_f32_16x16x32_bf16(pf, vf, oacc[hf], 0, 0, 0);
    }
  }
  const int b = bh >> 4, h = bh & 15;
#pragma unroll
  for (int hf = 0; hf < 4; hf++) {
#pragma unroll
    for (int r = 0; r < 4; r++) {
      int srow = qbase + 4 * g + r;
      float val = oacc[hf][r] / lrun[r];
      Om[((size_t)b * SDIM + srow) * DDIM + h * HDHD + hf * 16 + il] = f2bf(val);
    }
  }
}

extern "C" void kernel_launch(void* const* d_in, const int* in_sizes, int n_in,
                              void* d_out, int out_size, void* d_ws, size_t ws_size,
                              hipStream_t stream) {
  const float* hidden = (const float*)d_in[0];
  const float* attn_w = (const float*)d_in[1];
  const float* attn_b = (const float*)d_in[2];
  const float* proj_w = (const float*)d_in[3];
  const float* proj_b = (const float*)d_in[4];
  const float* projectors = (const float*)d_in[5];
  float* out = (float*)d_out;
  char* ws = (char*)d_ws;
  (void)in_sizes; (void)n_in; (void)out_size; (void)ws_size;

  unsigned short* hseq   = (unsigned short*)(ws);               // [4096][1024] bf16  8 MB
  unsigned short* wqkvT  = (unsigned short*)(ws + 8388608);     // [3072][1024] bf16  6 MB
  unsigned short* qb     = (unsigned short*)(ws + 14680064);    // [B,H,S,HD] bf16    8 MB
  unsigned short* kb     = (unsigned short*)(ws + 23068672);    // 8 MB
  unsigned short* vb     = (unsigned short*)(ws + 31457280);    // 8 MB
  unsigned short* attnM  = (unsigned short*)(ws + 39845888);    // [4096][1024] bf16  8 MB
  unsigned short* wprojT = (unsigned short*)(ws + 48234496);    // [1024][1024] bf16  2 MB

  cvt_hidden<<<dim3(4096), dim3(256), 0, stream>>>(hidden, hseq);
  transpose_cvt<<<dim3(32, 96), dim3(256), 0, stream>>>(attn_w, wqkvT, 1024, 3072);
  make_wproj<<<dim3(16, 16), dim3(256), 0, stream>>>(projectors, proj_w, wprojT);
  gemm_bt<0><<<dim3(24, 32), dim3(256), 0, stream>>>(hseq, wqkvT, attn_b, nullptr,
                                                     qb, kb, vb, 4096, 3072, 1024);
  attn_kernel<<<dim3(32, 32), dim3(256), 0, stream>>>(qb, kb, vb, attnM);
  gemm_bt<1><<<dim3(8, 32), dim3(256), 0, stream>>>(attnM, wprojT, proj_b, out,
                                                    nullptr, nullptr, nullptr, 4096, 1024, 1024);
}

// Round 2
// 176.925 us; speedup vs baseline: 1.8125x; 1.8125x over previous
//
#include <hip/hip_runtime.h>

typedef __attribute__((ext_vector_type(8))) short bhalf8;   // 8 bf16 MFMA operand
typedef __attribute__((ext_vector_type(4))) float f32x4;
typedef __attribute__((ext_vector_type(8))) unsigned short u16x8;
typedef __attribute__((ext_vector_type(4))) unsigned short u16x4;

#define BDIM 2
#define SDIM 2048
#define DDIM 1024
#define HDIM 16
#define HDHD 64

__device__ __forceinline__ unsigned short f2bf(float f) {
  unsigned u = __builtin_bit_cast(unsigned, f);
  u += 0x7fffu + ((u >> 16) & 1u);           // RNE
  return (unsigned short)(u >> 16);
}

// ---------------- elementwise f32 -> bf16 ----------------
__global__ __launch_bounds__(256) void cvt_hidden(const float* __restrict__ x,
                                                  unsigned short* __restrict__ y) {
  size_t i = ((size_t)blockIdx.x * 256 + threadIdx.x) * 4;
  f32x4 v = *(const f32x4*)(x + i);
  u16x4 o;
  o[0] = f2bf(v[0]); o[1] = f2bf(v[1]); o[2] = f2bf(v[2]); o[3] = f2bf(v[3]);
  *(u16x4*)(y + i) = o;
}

// ---------------- transpose + convert: W[R][C] f32 -> Wt[C][R] bf16 ----------------
__global__ __launch_bounds__(256) void transpose_cvt(const float* __restrict__ W,
                                                     unsigned short* __restrict__ Wt,
                                                     int R, int C) {
  __shared__ float tl[32][33];
  int rt = blockIdx.x * 32, ct = blockIdx.y * 32;
  int r8 = threadIdx.x >> 5, c = threadIdx.x & 31;
#pragma unroll
  for (int i = 0; i < 4; i++)
    tl[r8 + i * 8][c] = W[(size_t)(rt + r8 + i * 8) * C + ct + c];
  __syncthreads();
#pragma unroll
  for (int i = 0; i < 4; i++)
    Wt[(size_t)(ct + r8 + i * 8) * R + rt + c] = f2bf(tl[c][r8 + i * 8]);
}

// ------- W'^T[o][h*64+d] = sum_e P[h][d][e] * Wproj[h*64+e][o]  (bf16 out) -------
__global__ __launch_bounds__(256) void make_wproj(const float* __restrict__ proj,
                                                  const float* __restrict__ wproj,
                                                  unsigned short* __restrict__ WT) {
  int h = blockIdx.x, ot = blockIdx.y * 64;
  __shared__ float Pl[64][65];
  __shared__ float Wl[64][65];
  int t = threadIdx.x;
#pragma unroll
  for (int i = 0; i < 16; i++) {
    int idx = t + 256 * i;                  // 0..4095
    int a = idx >> 6, bc = idx & 63;
    Pl[a][bc] = proj[(size_t)h * 4096 + idx];
    Wl[a][bc] = wproj[(size_t)(h * 64 + a) * 1024 + ot + bc];
  }
  __syncthreads();
  int d = t & 63, ob = t >> 6;              // lanes vary d -> coalesced writes
#pragma unroll
  for (int i = 0; i < 16; i++) {
    int o = ob + i * 4;
    float acc = 0.f;
#pragma unroll
    for (int e = 0; e < 64; e++) acc += Pl[d][e] * Wl[e][o];
    WT[(size_t)(ot + o) * 1024 + h * 64 + d] = f2bf(acc);
  }
}

// ---------------- bf16 GEMM, Bt layout: C[M,N] = A[M,K] @ Bt[N,K]^T + bias ----------------
// EPI 0: split into q(,*0.125)/k/v  [B,H,S,HD] bf16.  EPI 1: f32 out row-major.
template <int EPI>
__global__ __launch_bounds__(256) void gemm_bt(
    const unsigned short* __restrict__ A, const unsigned short* __restrict__ Bt,
    const float* __restrict__ bias, float* __restrict__ Cf,
    unsigned short* __restrict__ q, unsigned short* __restrict__ k,
    unsigned short* __restrict__ v, int M, int N, int K) {
  __shared__ unsigned short As[128][72];
  __shared__ unsigned short Bs[128][72];
  const int tid = threadIdx.x;
  const int m0 = blockIdx.y * 128, n0 = blockIdx.x * 128;
  f32x4 acc[4][4];
#pragma unroll
  for (int m = 0; m < 4; m++)
#pragma unroll
    for (int n = 0; n < 4; n++) acc[m][n] = f32x4{0.f, 0.f, 0.f, 0.f};
  const int w = tid >> 6, lane = tid & 63;
  const int wr = (w >> 1) * 64, wc = (w & 1) * 64;
  const int lrow = lane & 15, lk = (lane >> 4) * 8;

  for (int kt = 0; kt < K; kt += 64) {
    __syncthreads();
#pragma unroll
    for (int i = 0; i < 4; i++) {
      int cch = tid + 256 * i;              // 0..1023 chunks of 8 bf16
      int r = cch >> 3, c8 = cch & 7;
      *(u16x8*)(&As[r][c8 * 8]) = *(const u16x8*)(A + (size_t)(m0 + r) * K + kt + c8 * 8);
      *(u16x8*)(&Bs[r][c8 * 8]) = *(const u16x8*)(Bt + (size_t)(n0 + r) * K + kt + c8 * 8);
    }
    __syncthreads();
#pragma unroll
    for (int kk = 0; kk < 2; kk++) {
      bhalf8 af[4], bfr[4];
#pragma unroll
      for (int m = 0; m < 4; m++) af[m] = *(const bhalf8*)(&As[wr + m * 16 + lrow][kk * 32 + lk]);
#pragma unroll
      for (int n = 0; n < 4; n++) bfr[n] = *(const bhalf8*)(&Bs[wc + n * 16 + lrow][kk * 32 + lk]);
#pragma unroll
      for (int m = 0; m < 4; m++)
#pragma unroll
        for (int n = 0; n < 4; n++)
          acc[m][n] = __builtin_amdgcn_mfma_f32_16x16x32_bf16(af[m], bfr[n], acc[m][n], 0, 0, 0);
    }
  }
  // epilogue: D row = 4*(lane>>4)+r, col = lane&15 within each 16x16 frag
  const int g = lane >> 4, il = lane & 15;
#pragma unroll
  for (int m = 0; m < 4; m++) {
    int rowb = wr + m * 16 + 4 * g;
#pragma unroll
    for (int n = 0; n < 4; n++) {
      int col = n0 + wc + n * 16 + il;
      float bs = bias[col];
#pragma unroll
      for (int r = 0; r < 4; r++) {
        int row = m0 + rowb + r;
        float val = acc[m][n][r] + bs;
        if (EPI == 0) {
          int which = col >> 10, hh = (col >> 6) & 15, hd = col & 63;
          int b = row >> 11, s = row & 2047;
          size_t idx = ((size_t)(b * 16 + hh) * SDIM + s) * HDHD + hd;
          unsigned short bv = f2bf(which == 0 ? val * 0.125f : val);
          if (which == 0) q[idx] = bv;
          else if (which == 1) k[idx] = bv;
          else v[idx] = bv;
        } else {
          Cf[(size_t)row * N + col] = val;
        }
      }
    }
  }
}

// ---------------- causal flash attention, 64-row q blocks, KVBLK=64 ----------------
// Per wave: 16 q-rows. LDS strides are 72 u16 (144 B = 36 dwords) so every b128
// access lands 8 lanes per 4-bank group (the b128 minimum = conflict-free).
__global__ __launch_bounds__(256, 4) void attn_kernel(const unsigned short* __restrict__ Q,
                                                      const unsigned short* __restrict__ Kb,
                                                      const unsigned short* __restrict__ Vb,
                                                      unsigned short* __restrict__ Om) {
  __shared__ unsigned short Ks[64][72];
  __shared__ unsigned short Vt[64][72];        // V transposed: Vt[d][k]
  __shared__ unsigned short Ps[4][16][72];     // per-wave P tile (16 q x 64 k)
  const int bh = blockIdx.x;                   // b*16+h
  const int qt = 31 - blockIdx.y;              // longest blocks dispatch first
  const int tid = threadIdx.x;
  const int w = tid >> 6, lane = tid & 63;
  const int g = lane >> 4, il = lane & 15;
  const int qbase = qt * 64 + w * 16;
  const size_t bhS = (size_t)bh * SDIM;

  // Q fragments (q pre-scaled by 1/8 in the QKV epilogue)
  bhalf8 qf0, qf1;
  {
    const unsigned short* qp = Q + (bhS + qbase + il) * HDHD + g * 8;
    qf0 = *(const bhalf8*)(qp);
    qf1 = *(const bhalf8*)(qp + 32);
  }
  f32x4 oacc[4];
#pragma unroll
  for (int i = 0; i < 4; i++) oacc[i] = f32x4{0.f, 0.f, 0.f, 0.f};
  float mrun[4], lrun[4];
#pragma unroll
  for (int r = 0; r < 4; r++) { mrun[r] = -1e30f; lrun[r] = 0.f; }

  const int srow = tid >> 2;                   // K staging: row 0..63
  const int schk = (tid & 3) * 16;             // 16-u16 col chunk
  const int nt = qt + 1;                       // causal: tiles 0..qt

  for (int kt = 0; kt < nt; kt++) {
    const size_t kbase = (bhS + (size_t)kt * 64) * HDHD;
    __syncthreads();
    // --- stage K rows (coalesced 32B/thread, conflict-free b128 LDS writes) ---
    {
      const unsigned short* src = Kb + kbase + srow * HDHD + schk;
      *(u16x8*)(&Ks[srow][schk]) = *(const u16x8*)(src);
      *(u16x8*)(&Ks[srow][schk + 8]) = *(const u16x8*)(src + 8);
    }
    // --- stage V transposed: lane=d gathers 16 k's (each load coalesced 128B/wave) ---
    {
      const unsigned short* vsrc = Vb + kbase + (size_t)(w * 16) * HDHD + lane;
      u16x8 va, vb2;
#pragma unroll
      for (int i = 0; i < 8; i++) va[i] = vsrc[i * HDHD];
#pragma unroll
      for (int i = 0; i < 8; i++) vb2[i] = vsrc[(8 + i) * HDHD];
      *(u16x8*)(&Vt[lane][w * 16]) = va;
      *(u16x8*)(&Vt[lane][w * 16 + 8]) = vb2;
    }
    __syncthreads();
    // --- S = Q @ K^T : 4 col-frags x 2 k-chunks = 8 MFMA ---
    f32x4 s[4];
#pragma unroll
    for (int c = 0; c < 4; c++) s[c] = f32x4{0.f, 0.f, 0.f, 0.f};
#pragma unroll
    for (int c = 0; c < 4; c++) {
      bhalf8 k0 = *(const bhalf8*)(&Ks[c * 16 + il][g * 8]);
      bhalf8 k1 = *(const bhalf8*)(&Ks[c * 16 + il][32 + g * 8]);
      s[c] = __builtin_amdgcn_mfma_f32_16x16x32_bf16(qf0, k0, s[c], 0, 0, 0);
      s[c] = __builtin_amdgcn_mfma_f32_16x16x32_bf16(qf1, k1, s[c], 0, 0, 0);
    }
    const bool diag = (kt == qt);
    const int kc0 = kt * 64 + il;
    // --- online softmax (wave-parallel, 16-lane groups) ---
#pragma unroll
    for (int r = 0; r < 4; r++) {
      float v0 = s[0][r], v1 = s[1][r], v2 = s[2][r], v3 = s[3][r];
      if (diag) {
        int qr = qbase + 4 * g + r;
        if (kc0 > qr) v0 = -1e30f;
        if (kc0 + 16 > qr) v1 = -1e30f;
        if (kc0 + 32 > qr) v2 = -1e30f;
        if (kc0 + 48 > qr) v3 = -1e30f;
      }
      float mx = fmaxf(fmaxf(v0, v1), fmaxf(v2, v3));
      mx = fmaxf(mx, __shfl_xor(mx, 1));
      mx = fmaxf(mx, __shfl_xor(mx, 2));
      mx = fmaxf(mx, __shfl_xor(mx, 4));
      mx = fmaxf(mx, __shfl_xor(mx, 8));
      float mn = fmaxf(mrun[r], mx);
      float sc = __expf(mrun[r] - mn);
      mrun[r] = mn;
      float p0 = __expf(v0 - mn), p1 = __expf(v1 - mn);
      float p2 = __expf(v2 - mn), p3 = __expf(v3 - mn);
      float rs = p0 + p1 + p2 + p3;
      rs += __shfl_xor(rs, 1);
      rs += __shfl_xor(rs, 2);
      rs += __shfl_xor(rs, 4);
      rs += __shfl_xor(rs, 8);
      lrun[r] = lrun[r] * sc + rs;
      int pr = 4 * g + r;
      Ps[w][pr][il] = f2bf(p0);
      Ps[w][pr][16 + il] = f2bf(p1);
      Ps[w][pr][32 + il] = f2bf(p2);
      Ps[w][pr][48 + il] = f2bf(p3);
#pragma unroll
      for (int df = 0; df < 4; df++) oacc[df][r] *= sc;
    }
    // --- O += P @ V : 4 d-frags x 2 k-chunks = 8 MFMA ---
#pragma unroll
    for (int kk = 0; kk < 2; kk++) {
      bhalf8 pf = *(const bhalf8*)(&Ps[w][il][kk * 32 + g * 8]);
#pragma unroll
      for (int df = 0; df < 4; df++) {
        bhalf8 vf = *(const bhalf8*)(&Vt[df * 16 + il][kk * 32 + g * 8]);
        oacc[df] = __builtin_amdgcn_mfma_f32_16x16x32_bf16(pf, vf, oacc[df], 0, 0, 0);
      }
    }
  }
  // --- epilogue: merged [B*S][D] bf16 ---
  const int b = bh >> 4, h = bh & 15;
#pragma unroll
  for (int r = 0; r < 4; r++) {
    int srow2 = qbase + 4 * g + r;
    float inv = 1.f / lrun[r];
#pragma unroll
    for (int df = 0; df < 4; df++) {
      Om[((size_t)b * SDIM + srow2) * DDIM + h * HDHD + df * 16 + il] =
          f2bf(oacc[df][r] * inv);
    }
  }
}

extern "C" void kernel_launch(void* const* d_in, const int* in_sizes, int n_in,
                              void* d_out, int out_size, void* d_ws, size_t ws_size,
                              hipStream_t stream) {
  const float* hidden = (const float*)d_in[0];
  const float* attn_w = (const float*)d_in[1];
  const float* attn_b = (const float*)d_in[2];
  const float* proj_w = (const float*)d_in[3];
  const float* proj_b = (const float*)d_in[4];
  const float* projectors = (const float*)d_in[5];
  float* out = (float*)d_out;
  char* ws = (char*)d_ws;
  (void)in_sizes; (void)n_in; (void)out_size; (void)ws_size;

  unsigned short* hseq   = (unsigned short*)(ws);               // [4096][1024] bf16  8 MB
  unsigned short* wqkvT  = (unsigned short*)(ws + 8388608);     // [3072][1024] bf16  6 MB
  unsigned short* qb     = (unsigned short*)(ws + 14680064);    // [B,H,S,HD] bf16    8 MB
  unsigned short* kb     = (unsigned short*)(ws + 23068672);    // 8 MB
  unsigned short* vb     = (unsigned short*)(ws + 31457280);    // 8 MB
  unsigned short* attnM  = (unsigned short*)(ws + 39845888);    // [4096][1024] bf16  8 MB
  unsigned short* wprojT = (unsigned short*)(ws + 48234496);    // [1024][1024] bf16  2 MB

  cvt_hidden<<<dim3(4096), dim3(256), 0, stream>>>(hidden, hseq);
  transpose_cvt<<<dim3(32, 96), dim3(256), 0, stream>>>(attn_w, wqkvT, 1024, 3072);
  make_wproj<<<dim3(16, 16), dim3(256), 0, stream>>>(projectors, proj_w, wprojT);
  gemm_bt<0><<<dim3(24, 32), dim3(256), 0, stream>>>(hseq, wqkvT, attn_b, nullptr,
                                                     qb, kb, vb, 4096, 3072, 1024);
  attn_kernel<<<dim3(32, 32), dim3(256), 0, stream>>>(qb, kb, vb, attnM);
  gemm_bt<1><<<dim3(8, 32), dim3(256), 0, stream>>>(attnM, wprojT, proj_b, out,
                                                    nullptr, nullptr, nullptr, 4096, 1024, 1024);
}